// Round 1
// baseline (2723.895 us; speedup 1.0000x reference)
//
#include <hip/hip_runtime.h>
#include <math.h>

#define D_MODEL 1024
#define NHEADS  16
#define NKV     4
#define HDIM    64
#define KVDIM   256   // NKV * HDIM
#define BB      2
#define NN      2048
#define MROWS   (BB*NN)   // 4096

// ---------------------------------------------------------------------------
// Tiled fp32 GEMM: C[M,Nc] = A[M,K] @ W[K,Nc].  128x128 tile, BK=16,
// 256 threads, 8x8 accum per thread. M,Nc,K all multiples of 128/128/16 here.
// ---------------------------------------------------------------------------
__global__ __launch_bounds__(256)
void gemm_f32(const float* __restrict__ A, const float* __restrict__ W,
              float* __restrict__ C, int M, int Nc, int K)
{
    __shared__ float As[16][128];   // As[k][m] (transposed A tile)
    __shared__ float Ws[16][128];   // Ws[k][n]

    const int tid = threadIdx.x;
    const int tx = tid & 15;        // n-direction
    const int ty = tid >> 4;        // m-direction
    const int rowBase = blockIdx.y * 128;
    const int colBase = blockIdx.x * 128;

    float acc[8][8];
#pragma unroll
    for (int i = 0; i < 8; i++)
#pragma unroll
        for (int j = 0; j < 8; j++) acc[i][j] = 0.f;

    // A-tile load mapping: each thread loads 8 consecutive k of one row
    const int am = tid >> 1;            // 0..127
    const int ak = (tid & 1) * 8;       // 0 or 8
    // W-tile load mapping: each thread loads 8 consecutive cols of one k-row
    const int wr = tid >> 4;            // 0..15
    const int wc = (tid & 15) * 8;      // 0..120

    const float* Aptr = A + (size_t)(rowBase + am) * K + ak;
    const float* Wptr = W + (size_t)wr * Nc + colBase + wc;

    for (int k0 = 0; k0 < K; k0 += 16) {
        float4 a0 = *(const float4*)(Aptr + k0);
        float4 a1 = *(const float4*)(Aptr + k0 + 4);
        float4 w0 = *(const float4*)(Wptr + (size_t)k0 * Nc);
        float4 w1 = *(const float4*)(Wptr + (size_t)k0 * Nc + 4);

        __syncthreads();   // previous compute done before overwrite
        As[ak + 0][am] = a0.x; As[ak + 1][am] = a0.y;
        As[ak + 2][am] = a0.z; As[ak + 3][am] = a0.w;
        As[ak + 4][am] = a1.x; As[ak + 5][am] = a1.y;
        As[ak + 6][am] = a1.z; As[ak + 7][am] = a1.w;
        *(float4*)&Ws[wr][wc]     = w0;
        *(float4*)&Ws[wr][wc + 4] = w1;
        __syncthreads();

#pragma unroll
        for (int kk = 0; kk < 16; kk++) {
            float4 aL = *(const float4*)&As[kk][ty * 8];
            float4 aH = *(const float4*)&As[kk][ty * 8 + 4];
            float4 wL = *(const float4*)&Ws[kk][tx * 8];
            float4 wH = *(const float4*)&Ws[kk][tx * 8 + 4];
            float av[8] = {aL.x, aL.y, aL.z, aL.w, aH.x, aH.y, aH.z, aH.w};
            float wv[8] = {wL.x, wL.y, wL.z, wL.w, wH.x, wH.y, wH.z, wH.w};
#pragma unroll
            for (int i = 0; i < 8; i++)
#pragma unroll
                for (int j = 0; j < 8; j++)
                    acc[i][j] = fmaf(av[i], wv[j], acc[i][j]);
        }
    }

#pragma unroll
    for (int i = 0; i < 8; i++) {
        float* cp = C + (size_t)(rowBase + ty * 8 + i) * Nc + colBase + tx * 8;
        *(float4*)cp       = make_float4(acc[i][0], acc[i][1], acc[i][2], acc[i][3]);
        *(float4*)(cp + 4) = make_float4(acc[i][4], acc[i][5], acc[i][6], acc[i][7]);
    }
}

// ---------------------------------------------------------------------------
// In-place RoPE (interleaved-pair variant):
//   out[j]    = t[2j]*cos[j] - t[2j+1]*sin[j]      (j < 32)
//   out[j+32] = t[2j]*sin[j] + t[2j+1]*cos[j]
// One thread per (row, head, j). Each head's 32 threads are contiguous and
// lie inside one 64-lane wave, so loads (all lanes) complete before stores
// (in-order wave execution) -> in-place is safe.
// ---------------------------------------------------------------------------
__global__ __launch_bounds__(256)
void rope_kernel(float* __restrict__ T, const float* __restrict__ Cos,
                 const float* __restrict__ Sin, int heads)
{
    const int tid = blockIdx.x * 256 + threadIdx.x;
    const int j   = tid & 31;
    const int ph  = tid >> 5;          // row*heads + h
    const int h   = ph % heads;
    const int row = ph / heads;
    const int n   = row % NN;

    float* t = T + (size_t)row * (heads * HDIM) + h * HDIM;
    const float e = t[2 * j];
    const float o = t[2 * j + 1];
    const float c = Cos[n * (HDIM / 2) + j];
    const float s = Sin[n * (HDIM / 2) + j];
    t[j]      = fmaf(e, c, -(o * s));
    t[j + 32] = fmaf(e, s,   o * c);
}

// ---------------------------------------------------------------------------
// Flash-style attention, fp32. One block per (q-tile of 128 rows, head, b).
// One thread per q row; K/V tiles (32 x 64) staged in LDS; online softmax.
// GQA: q head h uses kv head h>>2.
// ---------------------------------------------------------------------------
__global__ __launch_bounds__(128)
void attn_kernel(const float* __restrict__ Q, const float* __restrict__ K,
                 const float* __restrict__ V, float* __restrict__ O)
{
    const int qt  = blockIdx.x;
    const int h   = blockIdx.y;
    const int b   = blockIdx.z;
    const int kvh = h >> 2;
    const int tid = threadIdx.x;
    const int row = qt * 128 + tid;

    const float* qr = Q + ((size_t)(b * NN) + row) * D_MODEL + h * HDIM;
    const float* Kb = K + (size_t)b * NN * KVDIM + kvh * HDIM;
    const float* Vb = V + (size_t)b * NN * KVDIM + kvh * HDIM;

    __shared__ float Ks[32][64];
    __shared__ float Vs[32][64];

    float q[64];
#pragma unroll
    for (int d = 0; d < 64; d += 4) *(float4*)&q[d] = *(const float4*)&qr[d];
    float o[64];
#pragma unroll
    for (int d = 0; d < 64; d++) o[d] = 0.f;
    float mrun = -1e30f, l = 0.f;

    // tile-load mapping: 32 rows x 64 cols, 128 threads -> 16 floats each
    const int lr = tid >> 2;           // 0..31
    const int lc = (tid & 3) * 16;     // 0,16,32,48
    const float* kr = Kb + (size_t)lr * KVDIM + lc;
    const float* vr = Vb + (size_t)lr * KVDIM + lc;

    for (int k0 = 0; k0 < NN; k0 += 32) {
        __syncthreads();
#pragma unroll
        for (int i = 0; i < 16; i += 4) {
            *(float4*)&Ks[lr][lc + i] = *(const float4*)(kr + (size_t)k0 * KVDIM + i);
            *(float4*)&Vs[lr][lc + i] = *(const float4*)(vr + (size_t)k0 * KVDIM + i);
        }
        __syncthreads();

        float s[32];
#pragma unroll
        for (int kk = 0; kk < 32; kk++) {
            const float4* kp = (const float4*)&Ks[kk][0];
            float accd = 0.f;
#pragma unroll
            for (int d4 = 0; d4 < 16; d4++) {
                float4 kv = kp[d4];
                accd = fmaf(q[d4 * 4 + 0], kv.x, accd);
                accd = fmaf(q[d4 * 4 + 1], kv.y, accd);
                accd = fmaf(q[d4 * 4 + 2], kv.z, accd);
                accd = fmaf(q[d4 * 4 + 3], kv.w, accd);
            }
            s[kk] = accd * 0.125f;   // HEAD_DIM^-0.5
        }

        float tmax = mrun;
#pragma unroll
        for (int kk = 0; kk < 32; kk++) tmax = fmaxf(tmax, s[kk]);
        const float alpha = __expf(mrun - tmax);
        mrun = tmax;
        l *= alpha;
#pragma unroll
        for (int kk = 0; kk < 32; kk++) {
            float p = __expf(s[kk] - mrun);
            s[kk] = p;
            l += p;
        }
#pragma unroll
        for (int d = 0; d < 64; d++) o[d] *= alpha;
#pragma unroll
        for (int kk = 0; kk < 32; kk++) {
            const float4* vp = (const float4*)&Vs[kk][0];
            const float p = s[kk];
#pragma unroll
            for (int d4 = 0; d4 < 16; d4++) {
                float4 vv = vp[d4];
                o[d4 * 4 + 0] = fmaf(p, vv.x, o[d4 * 4 + 0]);
                o[d4 * 4 + 1] = fmaf(p, vv.y, o[d4 * 4 + 1]);
                o[d4 * 4 + 2] = fmaf(p, vv.z, o[d4 * 4 + 2]);
                o[d4 * 4 + 3] = fmaf(p, vv.w, o[d4 * 4 + 3]);
            }
        }
    }

    const float inv = 1.0f / l;
    float* orow = O + ((size_t)(b * NN) + row) * D_MODEL + h * HDIM;
#pragma unroll
    for (int d = 0; d < 64; d += 4) {
        *(float4*)&orow[d] = make_float4(o[d] * inv, o[d + 1] * inv,
                                         o[d + 2] * inv, o[d + 3] * inv);
    }
}

// ---------------------------------------------------------------------------
extern "C" void kernel_launch(void* const* d_in, const int* in_sizes, int n_in,
                              void* d_out, int out_size, void* d_ws, size_t ws_size,
                              hipStream_t stream)
{
    const float* x    = (const float*)d_in[0];
    const float* cosp = (const float*)d_in[1];
    const float* sinp = (const float*)d_in[2];
    const float* Wq   = (const float*)d_in[3];
    const float* Wk   = (const float*)d_in[4];
    const float* Wv   = (const float*)d_in[5];
    const float* Wo   = (const float*)d_in[6];
    float* out = (float*)d_out;

    float* Qb = (float*)d_ws;                         // 4096 x 1024
    float* Kb = Qb + (size_t)MROWS * D_MODEL;         // 4096 x 256
    float* Vb = Kb + (size_t)MROWS * KVDIM;           // 4096 x 256
    float* Ob = Vb + (size_t)MROWS * KVDIM;           // 4096 x 1024
    // total ws use: 10M floats = 40 MB

    gemm_f32<<<dim3(D_MODEL / 128, MROWS / 128), dim3(256), 0, stream>>>(
        x, Wq, Qb, MROWS, D_MODEL, D_MODEL);
    gemm_f32<<<dim3(KVDIM / 128, MROWS / 128), dim3(256), 0, stream>>>(
        x, Wk, Kb, MROWS, KVDIM, D_MODEL);
    gemm_f32<<<dim3(KVDIM / 128, MROWS / 128), dim3(256), 0, stream>>>(
        x, Wv, Vb, MROWS, KVDIM, D_MODEL);

    rope_kernel<<<(MROWS * NHEADS * 32) / 256, dim3(256), 0, stream>>>(
        Qb, cosp, sinp, NHEADS);
    rope_kernel<<<(MROWS * NKV * 32) / 256, dim3(256), 0, stream>>>(
        Kb, cosp, sinp, NKV);

    attn_kernel<<<dim3(NN / 128, NHEADS, BB), dim3(128), 0, stream>>>(
        Qb, Kb, Vb, Ob);

    gemm_f32<<<dim3(D_MODEL / 128, MROWS / 128), dim3(256), 0, stream>>>(
        Ob, Wo, out, MROWS, D_MODEL, D_MODEL);
}

// Round 2
// 1563.345 us; speedup vs baseline: 1.7424x; 1.7424x over previous
//
#include <hip/hip_runtime.h>
#include <math.h>

#define D_MODEL 1024
#define NHEADS  16
#define NKV     4
#define HDIM    64
#define KVDIM   256   // NKV * HDIM
#define BB      2
#define NN      2048
#define MROWS   (BB*NN)             // 4096
#define NTASK   (MROWS*NHEADS)      // 65536 q-row tasks

// ---------------------------------------------------------------------------
// Tiled fp32 GEMM: C[M,Nc] = A[M,K] @ W[K,Nc].  128x128 tile, BK=16,
// 256 threads, 8x8 accum per thread. (unchanged from round 1)
// ---------------------------------------------------------------------------
__global__ __launch_bounds__(256)
void gemm_f32(const float* __restrict__ A, const float* __restrict__ W,
              float* __restrict__ C, int M, int Nc, int K)
{
    __shared__ float As[16][128];   // As[k][m]
    __shared__ float Ws[16][128];   // Ws[k][n]

    const int tid = threadIdx.x;
    const int tx = tid & 15;
    const int ty = tid >> 4;
    const int rowBase = blockIdx.y * 128;
    const int colBase = blockIdx.x * 128;

    float acc[8][8];
#pragma unroll
    for (int i = 0; i < 8; i++)
#pragma unroll
        for (int j = 0; j < 8; j++) acc[i][j] = 0.f;

    const int am = tid >> 1;
    const int ak = (tid & 1) * 8;
    const int wr = tid >> 4;
    const int wc = (tid & 15) * 8;

    const float* Aptr = A + (size_t)(rowBase + am) * K + ak;
    const float* Wptr = W + (size_t)wr * Nc + colBase + wc;

    for (int k0 = 0; k0 < K; k0 += 16) {
        float4 a0 = *(const float4*)(Aptr + k0);
        float4 a1 = *(const float4*)(Aptr + k0 + 4);
        float4 w0 = *(const float4*)(Wptr + (size_t)k0 * Nc);
        float4 w1 = *(const float4*)(Wptr + (size_t)k0 * Nc + 4);

        __syncthreads();
        As[ak + 0][am] = a0.x; As[ak + 1][am] = a0.y;
        As[ak + 2][am] = a0.z; As[ak + 3][am] = a0.w;
        As[ak + 4][am] = a1.x; As[ak + 5][am] = a1.y;
        As[ak + 6][am] = a1.z; As[ak + 7][am] = a1.w;
        *(float4*)&Ws[wr][wc]     = w0;
        *(float4*)&Ws[wr][wc + 4] = w1;
        __syncthreads();

#pragma unroll
        for (int kk = 0; kk < 16; kk++) {
            float4 aL = *(const float4*)&As[kk][ty * 8];
            float4 aH = *(const float4*)&As[kk][ty * 8 + 4];
            float4 wL = *(const float4*)&Ws[kk][tx * 8];
            float4 wH = *(const float4*)&Ws[kk][tx * 8 + 4];
            float av[8] = {aL.x, aL.y, aL.z, aL.w, aH.x, aH.y, aH.z, aH.w};
            float wv[8] = {wL.x, wL.y, wL.z, wL.w, wH.x, wH.y, wH.z, wH.w};
#pragma unroll
            for (int i = 0; i < 8; i++)
#pragma unroll
                for (int j = 0; j < 8; j++)
                    acc[i][j] = fmaf(av[i], wv[j], acc[i][j]);
        }
    }

#pragma unroll
    for (int i = 0; i < 8; i++) {
        float* cp = C + (size_t)(rowBase + ty * 8 + i) * Nc + colBase + tx * 8;
        *(float4*)cp       = make_float4(acc[i][0], acc[i][1], acc[i][2], acc[i][3]);
        *(float4*)(cp + 4) = make_float4(acc[i][4], acc[i][5], acc[i][6], acc[i][7]);
    }
}

// ---------------------------------------------------------------------------
// In-place RoPE (unchanged from round 1).
// ---------------------------------------------------------------------------
__global__ __launch_bounds__(256)
void rope_kernel(float* __restrict__ T, const float* __restrict__ Cos,
                 const float* __restrict__ Sin, int heads)
{
    const int tid = blockIdx.x * 256 + threadIdx.x;
    const int j   = tid & 31;
    const int ph  = tid >> 5;
    const int h   = ph % heads;
    const int row = ph / heads;
    const int n   = row % NN;

    float* t = T + (size_t)row * (heads * HDIM) + h * HDIM;
    const float e = t[2 * j];
    const float o = t[2 * j + 1];
    const float c = Cos[n * (HDIM / 2) + j];
    const float s = Sin[n * (HDIM / 2) + j];
    t[j]      = fmaf(e, c, -(o * s));
    t[j + 32] = fmaf(e, s,   o * c);
}

// ---------------------------------------------------------------------------
// Split-K flash attention, fp32.
// Grid: (NN/128 row-tiles, NHEADS, BB*nsplit). Block: 256 threads.
// 2 threads per q-row: thread (2r+half) owns head-dims [half*32, half*32+32).
// Score = own 32-dim partial dot + __shfl_xor(partial, 1).
// Each block processes keys [sp*KPS, (sp+1)*KPS); writes unnormalized
// partial numerator + (m,l) to Part/ML.  nsplit==1 writes normalized to Ob.
// ---------------------------------------------------------------------------
__global__ __launch_bounds__(256)
void attn_split(const float* __restrict__ Q, const float* __restrict__ K,
                const float* __restrict__ V, float* __restrict__ Part,
                float2* __restrict__ ML, float* __restrict__ Ob, int nsplit)
{
    const int qt   = blockIdx.x;
    const int h    = blockIdx.y;
    const int b    = blockIdx.z / nsplit;
    const int sp   = blockIdx.z % nsplit;
    const int kvh  = h >> 2;
    const int tid  = threadIdx.x;
    const int half = tid & 1;
    const int rowL = tid >> 1;             // 0..127
    const int n    = qt * 128 + rowL;
    const int KPS  = NN / nsplit;
    const int key0 = sp * KPS;

    const float* qr = Q + ((size_t)(b * NN) + n) * D_MODEL + h * HDIM + half * 32;
    const float* Kb = K + (size_t)b * NN * KVDIM + kvh * HDIM;
    const float* Vb = V + (size_t)b * NN * KVDIM + kvh * HDIM;

    __shared__ float Ks[32][64];
    __shared__ float Vs[32][64];

    float q[32];
#pragma unroll
    for (int d = 0; d < 32; d += 4) *(float4*)&q[d] = *(const float4*)&qr[d];
    float o[32];
#pragma unroll
    for (int d = 0; d < 32; d++) o[d] = 0.f;
    float mrun = -1e30f, l = 0.f;

    // tile-load mapping: 32 rows x 64 cols, 256 threads -> 8 floats each
    const int lr = tid >> 3;               // 0..31
    const int lc = (tid & 7) * 8;          // 0..56
    const float* kr = Kb + (size_t)(key0 + lr) * KVDIM + lc;
    const float* vr = Vb + (size_t)(key0 + lr) * KVDIM + lc;

    for (int k0 = 0; k0 < KPS; k0 += 32) {
        __syncthreads();
        {
            const float* kp = kr + (size_t)k0 * KVDIM;
            const float* vp = vr + (size_t)k0 * KVDIM;
            *(float4*)&Ks[lr][lc]     = *(const float4*)kp;
            *(float4*)&Ks[lr][lc + 4] = *(const float4*)(kp + 4);
            *(float4*)&Vs[lr][lc]     = *(const float4*)vp;
            *(float4*)&Vs[lr][lc + 4] = *(const float4*)(vp + 4);
        }
        __syncthreads();

        float s[32];
#pragma unroll
        for (int kk = 0; kk < 32; kk++) {
            const float4* kp = (const float4*)&Ks[kk][half * 32];
            float a0 = 0.f, a1 = 0.f;
#pragma unroll
            for (int d4 = 0; d4 < 8; d4 += 2) {
                float4 k0v = kp[d4];
                float4 k1v = kp[d4 + 1];
                a0 = fmaf(q[d4 * 4 + 0], k0v.x, a0);
                a0 = fmaf(q[d4 * 4 + 1], k0v.y, a0);
                a0 = fmaf(q[d4 * 4 + 2], k0v.z, a0);
                a0 = fmaf(q[d4 * 4 + 3], k0v.w, a0);
                a1 = fmaf(q[d4 * 4 + 4], k1v.x, a1);
                a1 = fmaf(q[d4 * 4 + 5], k1v.y, a1);
                a1 = fmaf(q[d4 * 4 + 6], k1v.z, a1);
                a1 = fmaf(q[d4 * 4 + 7], k1v.w, a1);
            }
            float part = a0 + a1;
            // sum with partner thread (other 32 dims); fp add commutes so
            // both halves get bit-identical scores -> identical m,l.
            float full = part + __shfl_xor(part, 1, 64);
            s[kk] = full * 0.125f;     // HEAD_DIM^-0.5
        }

        float tmax = mrun;
#pragma unroll
        for (int kk = 0; kk < 32; kk++) tmax = fmaxf(tmax, s[kk]);
        const float alpha = __expf(mrun - tmax);
        mrun = tmax;
        l *= alpha;
#pragma unroll
        for (int kk = 0; kk < 32; kk++) {
            float p = __expf(s[kk] - mrun);
            s[kk] = p;
            l += p;
        }
#pragma unroll
        for (int d = 0; d < 32; d++) o[d] *= alpha;
#pragma unroll
        for (int kk = 0; kk < 32; kk++) {
            const float4* vp = (const float4*)&Vs[kk][half * 32];
            const float p = s[kk];
#pragma unroll
            for (int d4 = 0; d4 < 8; d4++) {
                float4 vv = vp[d4];
                o[d4 * 4 + 0] = fmaf(p, vv.x, o[d4 * 4 + 0]);
                o[d4 * 4 + 1] = fmaf(p, vv.y, o[d4 * 4 + 1]);
                o[d4 * 4 + 2] = fmaf(p, vv.z, o[d4 * 4 + 2]);
                o[d4 * 4 + 3] = fmaf(p, vv.w, o[d4 * 4 + 3]);
            }
        }
    }

    const size_t task = ((size_t)b * NHEADS + h) * NN + n;
    if (nsplit == 1) {
        const float inv = 1.0f / l;
        float* orow = Ob + ((size_t)(b * NN) + n) * D_MODEL + h * HDIM + half * 32;
#pragma unroll
        for (int d = 0; d < 32; d += 4)
            *(float4*)&orow[d] = make_float4(o[d] * inv, o[d + 1] * inv,
                                             o[d + 2] * inv, o[d + 3] * inv);
    } else {
        float* pp = Part + ((size_t)sp * NTASK + task) * 64 + half * 32;
#pragma unroll
        for (int d = 0; d < 32; d += 4)
            *(float4*)&pp[d] = make_float4(o[d], o[d + 1], o[d + 2], o[d + 3]);
        if (half == 0) ML[(size_t)sp * NTASK + task] = make_float2(mrun, l);
    }
}

// ---------------------------------------------------------------------------
// Combine split partials:  O = (sum_s e^{m_s-m} num_s) / (sum_s e^{m_s-m} l_s)
// One thread per (task, 4-dim group): NTASK*16 threads.
// ---------------------------------------------------------------------------
__global__ __launch_bounds__(256)
void attn_combine(const float* __restrict__ Part, const float2* __restrict__ ML,
                  float* __restrict__ Ob, int nsplit)
{
    const int gid  = blockIdx.x * 256 + threadIdx.x;
    const int task = gid >> 4;
    const int d    = (gid & 15) * 4;
    const int n    = task & (NN - 1);
    const int bh   = task >> 11;
    const int h    = bh & (NHEADS - 1);
    const int b    = bh >> 4;

    float2 ml[8];
    float m = -1e30f;
    for (int s = 0; s < nsplit; s++) {
        ml[s] = ML[(size_t)s * NTASK + task];
        m = fmaxf(m, ml[s].x);
    }
    float4 num = make_float4(0.f, 0.f, 0.f, 0.f);
    float l = 0.f;
    for (int s = 0; s < nsplit; s++) {
        const float w = __expf(ml[s].x - m);
        float4 p = *(const float4*)&Part[((size_t)s * NTASK + task) * 64 + d];
        num.x = fmaf(w, p.x, num.x);
        num.y = fmaf(w, p.y, num.y);
        num.z = fmaf(w, p.z, num.z);
        num.w = fmaf(w, p.w, num.w);
        l = fmaf(w, ml[s].y, l);
    }
    const float inv = 1.0f / l;
    float* op = Ob + ((size_t)(b * NN) + n) * D_MODEL + h * HDIM + d;
    *(float4*)op = make_float4(num.x * inv, num.y * inv, num.z * inv, num.w * inv);
}

// ---------------------------------------------------------------------------
extern "C" void kernel_launch(void* const* d_in, const int* in_sizes, int n_in,
                              void* d_out, int out_size, void* d_ws, size_t ws_size,
                              hipStream_t stream)
{
    const float* x    = (const float*)d_in[0];
    const float* cosp = (const float*)d_in[1];
    const float* sinp = (const float*)d_in[2];
    const float* Wq   = (const float*)d_in[3];
    const float* Wk   = (const float*)d_in[4];
    const float* Wv   = (const float*)d_in[5];
    const float* Wo   = (const float*)d_in[6];
    float* out = (float*)d_out;

    float* Qb = (float*)d_ws;                         // 4096 x 1024
    float* Kb = Qb + (size_t)MROWS * D_MODEL;         // 4096 x 256
    float* Vb = Kb + (size_t)MROWS * KVDIM;           // 4096 x 256
    float* Ob = Vb + (size_t)MROWS * KVDIM;           // 4096 x 1024
    float* Part = Ob + (size_t)MROWS * D_MODEL;       // S x NTASK x 64
    const size_t baseFloats = (size_t)MROWS * D_MODEL * 2 + (size_t)MROWS * KVDIM * 2;

    // pick largest split count whose partial buffers fit in ws
    // (ws_size is constant across calls -> same work every call)
    int S = 1;
    for (int cand = 8; cand >= 2; cand >>= 1) {
        size_t need = (baseFloats + (size_t)cand * NTASK * 64 +
                       (size_t)cand * NTASK * 2) * sizeof(float);
        if (need <= ws_size) { S = cand; break; }
    }
    float2* MLb = (float2*)(Part + (size_t)S * NTASK * 64);

    gemm_f32<<<dim3(D_MODEL / 128, MROWS / 128), dim3(256), 0, stream>>>(
        x, Wq, Qb, MROWS, D_MODEL, D_MODEL);
    gemm_f32<<<dim3(KVDIM / 128, MROWS / 128), dim3(256), 0, stream>>>(
        x, Wk, Kb, MROWS, KVDIM, D_MODEL);
    gemm_f32<<<dim3(KVDIM / 128, MROWS / 128), dim3(256), 0, stream>>>(
        x, Wv, Vb, MROWS, KVDIM, D_MODEL);

    rope_kernel<<<(MROWS * NHEADS * 32) / 256, dim3(256), 0, stream>>>(
        Qb, cosp, sinp, NHEADS);
    rope_kernel<<<(MROWS * NKV * 32) / 256, dim3(256), 0, stream>>>(
        Kb, cosp, sinp, NKV);

    attn_split<<<dim3(NN / 128, NHEADS, BB * S), dim3(256), 0, stream>>>(
        Qb, Kb, Vb, Part, MLb, Ob, S);
    if (S > 1) {
        attn_combine<<<(NTASK * 16) / 256, dim3(256), 0, stream>>>(
            Part, MLb, Ob, S);
    }

    gemm_f32<<<dim3(D_MODEL / 128, MROWS / 128), dim3(256), 0, stream>>>(
        Ob, Wo, out, MROWS, D_MODEL, D_MODEL);
}

// Round 3
// 386.517 us; speedup vs baseline: 7.0473x; 4.0447x over previous
//
#include <hip/hip_runtime.h>
#include <math.h>

#define D_MODEL 1024
#define NHEADS  16
#define NKV     4
#define HDIM    64
#define KVDIM   256
#define BB      2
#define NN      2048
#define MROWS   (BB*NN)        // 4096
#define QKVN    1536           // 1024 + 256 + 256

typedef unsigned short ushort_t;
typedef unsigned int uint_t;
typedef float  f32x4 __attribute__((ext_vector_type(4)));
typedef short  s16x8 __attribute__((ext_vector_type(8)));

#define MFMA16(A,B,C) __builtin_amdgcn_mfma_f32_16x16x32_bf16((A),(B),(C),0,0,0)

// fp32 -> bf16 round-to-nearest-even
__device__ __forceinline__ ushort_t f2b(float f) {
    uint_t u = __float_as_uint(f);
    u += 0x7FFFu + ((u >> 16) & 1u);
    return (ushort_t)(u >> 16);
}

// ---------------------------------------------------------------------------
// castx: fp32 -> bf16, 4 elements/thread
// ---------------------------------------------------------------------------
__global__ __launch_bounds__(256)
void cast_kernel(const float* __restrict__ src, ushort_t* __restrict__ dst, int n4)
{
    int i = blockIdx.x * 256 + threadIdx.x;
    if (i >= n4) return;
    float4 v = ((const float4*)src)[i];
    uint2 o;
    o.x = (uint_t)f2b(v.x) | ((uint_t)f2b(v.y) << 16);
    o.y = (uint_t)f2b(v.z) | ((uint_t)f2b(v.w) << 16);
    ((uint2*)dst)[i] = o;
}

// ---------------------------------------------------------------------------
// transpose + cast: src fp32 [K][N] -> dst bf16 [N][K]
// ---------------------------------------------------------------------------
__global__ __launch_bounds__(256)
void transpose_cast(const float* __restrict__ src, ushort_t* __restrict__ dst,
                    int K, int N)
{
    __shared__ float T[32][33];
    const int tx = threadIdx.x & 31, ty = threadIdx.x >> 5;
    const int n0 = blockIdx.x * 32, k0 = blockIdx.y * 32;
#pragma unroll
    for (int i = 0; i < 4; i++)
        T[ty + i * 8][tx] = src[(size_t)(k0 + ty + i * 8) * N + n0 + tx];
    __syncthreads();
#pragma unroll
    for (int i = 0; i < 4; i++)
        dst[(size_t)(n0 + ty + i * 8) * K + k0 + tx] = f2b(T[tx][ty + i * 8]);
}

// ---------------------------------------------------------------------------
// V transpose: QKVf cols [1280,1536) per batch -> Vt bf16 [(b*256+d)][2048]
// ---------------------------------------------------------------------------
__global__ __launch_bounds__(256)
void vtrans_kernel(const float* __restrict__ QKVf, ushort_t* __restrict__ Vt)
{
    __shared__ float T[32][33];
    const int tx = threadIdx.x & 31, ty = threadIdx.x >> 5;
    const int n0 = blockIdx.x * 32, d0 = blockIdx.y * 32, b = blockIdx.z;
#pragma unroll
    for (int i = 0; i < 4; i++)
        T[ty + i * 8][tx] =
            QKVf[(size_t)(b * NN + n0 + ty + i * 8) * QKVN + 1280 + d0 + tx];
    __syncthreads();
#pragma unroll
    for (int i = 0; i < 4; i++)
        Vt[(size_t)(b * 256 + d0 + ty + i * 8) * NN + n0 + tx] = f2b(T[tx][ty + i * 8]);
}

// ---------------------------------------------------------------------------
// RoPE + cast + relayout for Q and K (reads fp32 QKVf).
// Q gets scale 0.125*log2(e) folded in (softmax runs base-2).
// Qb: [(b*16+h)*2048+n][64], Kb: [(b*4+kvh)*2048+n][64]
// ---------------------------------------------------------------------------
#define NQW (MROWS*NHEADS*32)   // 2,097,152
#define NKW (MROWS*NKV*32)      //   524,288
__global__ __launch_bounds__(256)
void rope_kernel(const float* __restrict__ QKVf, const float* __restrict__ Cos,
                 const float* __restrict__ Sin, ushort_t* __restrict__ Qb,
                 ushort_t* __restrict__ Kb)
{
    const float SC = 0.125f * 1.44269504f;
    int idx = blockIdx.x * 256 + threadIdx.x;
    if (idx < NQW) {
        const int row = idx >> 9, rem = idx & 511;
        const int h = rem >> 5, j = rem & 31;
        const int b = row >> 11, n = row & (NN - 1);
        const float* s_ = QKVf + (size_t)row * QKVN + h * 64;
        const float e = s_[2 * j], o = s_[2 * j + 1];
        const float c = Cos[n * 32 + j], s = Sin[n * 32 + j];
        ushort_t* dst = Qb + ((size_t)(b * 16 + h) * NN + n) * 64;
        dst[j]      = f2b((e * c - o * s) * SC);
        dst[j + 32] = f2b((e * s + o * c) * SC);
    } else {
        const int i2 = idx - NQW;
        const int row = i2 >> 7, rem = i2 & 127;
        const int h = rem >> 5, j = rem & 31;
        const int b = row >> 11, n = row & (NN - 1);
        const float* s_ = QKVf + (size_t)row * QKVN + 1024 + h * 64;
        const float e = s_[2 * j], o = s_[2 * j + 1];
        const float c = Cos[n * 32 + j], s = Sin[n * 32 + j];
        ushort_t* dst = Kb + ((size_t)(b * 4 + h) * NN + n) * 64;
        dst[j]      = f2b(e * c - o * s);
        dst[j + 32] = f2b(e * s + o * c);
    }
}

// ---------------------------------------------------------------------------
// bf16 MFMA GEMM, B^T form: C[M][N] fp32 = A[M][K]bf16 * (Bt[N][K])^T.
// 128x128 tile, BK=32, 256 threads = 4 waves, wave computes 64x64 (4x4
// tiles of 16x16x32 MFMA). LDS rows padded to 40 bf16 (80B: 16B-aligned
// b128 reads, <=2-way bank conflicts).
// ---------------------------------------------------------------------------
__global__ __launch_bounds__(256)
void gemm_bt(const ushort_t* __restrict__ A, const ushort_t* __restrict__ Bt,
             float* __restrict__ C, int M, int N, int K)
{
    __shared__ ushort_t As[128][40];
    __shared__ ushort_t Bs[128][40];

    const int tid  = threadIdx.x;
    const int wave = tid >> 6, lane = tid & 63;
    const int quad = lane >> 4, l16 = lane & 15;
    const int rowBase = blockIdx.y * 128, colBase = blockIdx.x * 128;
    const int wm = (wave >> 1) * 64, wn = (wave & 1) * 64;

    f32x4 acc[4][4];
    const f32x4 zz = {0.f, 0.f, 0.f, 0.f};
#pragma unroll
    for (int i = 0; i < 4; i++)
#pragma unroll
        for (int j = 0; j < 4; j++) acc[i][j] = zz;

    const int r0 = tid >> 2;            // 0..63
    const int p0 = (tid & 3) * 8;       // 0,8,16,24
    const ushort_t* Ag = A  + (size_t)(rowBase + r0) * K + p0;
    const ushort_t* Bg = Bt + (size_t)(colBase + r0) * K + p0;

    for (int k0 = 0; k0 < K; k0 += 32) {
        uint4 a0 = *(const uint4*)(Ag + k0);
        uint4 a1 = *(const uint4*)(Ag + (size_t)64 * K + k0);
        uint4 b0 = *(const uint4*)(Bg + k0);
        uint4 b1 = *(const uint4*)(Bg + (size_t)64 * K + k0);
        __syncthreads();
        *(uint4*)&As[r0][p0]      = a0;
        *(uint4*)&As[r0 + 64][p0] = a1;
        *(uint4*)&Bs[r0][p0]      = b0;
        *(uint4*)&Bs[r0 + 64][p0] = b1;
        __syncthreads();

        s16x8 af[4], bf[4];
#pragma unroll
        for (int mt = 0; mt < 4; mt++)
            af[mt] = *(const s16x8*)&As[wm + mt * 16 + l16][quad * 8];
#pragma unroll
        for (int nt = 0; nt < 4; nt++)
            bf[nt] = *(const s16x8*)&Bs[wn + nt * 16 + l16][quad * 8];
#pragma unroll
        for (int mt = 0; mt < 4; mt++)
#pragma unroll
            for (int nt = 0; nt < 4; nt++)
                acc[mt][nt] = MFMA16(af[mt], bf[nt], acc[mt][nt]);
    }

#pragma unroll
    for (int mt = 0; mt < 4; mt++)
#pragma unroll
        for (int nt = 0; nt < 4; nt++) {
            const int row = rowBase + wm + mt * 16 + quad * 4;
            const int col = colBase + wn + nt * 16 + l16;
#pragma unroll
            for (int r = 0; r < 4; r++)
                C[(size_t)(row + r) * N + col] = acc[mt][nt][r];
        }
}

// ---------------------------------------------------------------------------
// MFMA flash attention. Block = (64 q-rows, head, batch); 4 waves of 16 rows.
// Q frags in registers; K/V frags loaded from global (L2-resident);
// P transits C-layout -> A-layout via wave-private LDS (no barriers at all).
// Scores already scaled by 0.125*log2e (folded into Q); softmax in base 2.
// Writes Ob bf16 [b*2048+n][1024].
// ---------------------------------------------------------------------------
__global__ __launch_bounds__(256)
void attn_mfma(const ushort_t* __restrict__ Qb, const ushort_t* __restrict__ Kb,
               const ushort_t* __restrict__ Vt, ushort_t* __restrict__ Ob)
{
    const int qt = blockIdx.x, h = blockIdx.y, b = blockIdx.z;
    const int kvh = h >> 2;
    const int tid = threadIdx.x;
    const int wave = tid >> 6, lane = tid & 63;
    const int quad = lane >> 4, l16 = lane & 15;

    __shared__ ushort_t Ps[4][16 * 72];
    ushort_t* ps = &Ps[wave][0];

    const int row0 = qt * 64 + wave * 16;
    const ushort_t* qp = Qb + ((size_t)(b * 16 + h) * NN + row0 + l16) * 64 + quad * 8;
    const s16x8 qf0 = *(const s16x8*)qp;
    const s16x8 qf1 = *(const s16x8*)(qp + 32);

    const ushort_t* kbase = Kb + (size_t)(b * 4 + kvh) * NN * 64;
    const ushort_t* vbase = Vt + (size_t)(b * 256 + kvh * 64) * NN;

    const f32x4 zz = {0.f, 0.f, 0.f, 0.f};
    f32x4 o[4] = {zz, zz, zz, zz};
    float m[4] = {-1e30f, -1e30f, -1e30f, -1e30f};
    float l[4] = {0.f, 0.f, 0.f, 0.f};

    for (int key0 = 0; key0 < NN; key0 += 64) {
        // ---- S = Q K^T (64 keys), C-layout: row=quad*4+r, col=nt*16+l16
        f32x4 s[4];
#pragma unroll
        for (int nt = 0; nt < 4; nt++) {
            const ushort_t* kp = kbase + (size_t)(key0 + nt * 16 + l16) * 64 + quad * 8;
            s16x8 kf0 = *(const s16x8*)kp;
            s16x8 kf1 = *(const s16x8*)(kp + 32);
            s[nt] = MFMA16(qf0, kf0, zz);
            s[nt] = MFMA16(qf1, kf1, s[nt]);
        }
        // ---- online softmax (base 2), stats per row r
        float mx[4];
#pragma unroll
        for (int r = 0; r < 4; r++)
            mx[r] = fmaxf(fmaxf(s[0][r], s[1][r]), fmaxf(s[2][r], s[3][r]));
#pragma unroll
        for (int mk = 1; mk <= 8; mk <<= 1)
#pragma unroll
            for (int r = 0; r < 4; r++)
                mx[r] = fmaxf(mx[r], __shfl_xor(mx[r], mk, 64));
        float al[4];
#pragma unroll
        for (int r = 0; r < 4; r++) {
            float mn = fmaxf(m[r], mx[r]);
            al[r] = exp2f(m[r] - mn);
            m[r] = mn;
        }
        f32x4 p[4];
        float rs[4] = {0.f, 0.f, 0.f, 0.f};
#pragma unroll
        for (int nt = 0; nt < 4; nt++)
#pragma unroll
            for (int r = 0; r < 4; r++) {
                float pv = exp2f(s[nt][r] - m[r]);
                p[nt][r] = pv;
                rs[r] += pv;
            }
#pragma unroll
        for (int mk = 1; mk <= 8; mk <<= 1)
#pragma unroll
            for (int r = 0; r < 4; r++)
                rs[r] += __shfl_xor(rs[r], mk, 64);
#pragma unroll
        for (int r = 0; r < 4; r++) l[r] = l[r] * al[r] + rs[r];
#pragma unroll
        for (int nt = 0; nt < 4; nt++)
#pragma unroll
            for (int r = 0; r < 4; r++) o[nt][r] *= al[r];

        // ---- P: C-layout -> A-layout via wave-private LDS (stride 72)
#pragma unroll
        for (int nt = 0; nt < 4; nt++)
#pragma unroll
            for (int r = 0; r < 4; r++)
                ps[(quad * 4 + r) * 72 + nt * 16 + l16] = f2b(p[nt][r]);

        s16x8 pa0 = *(const s16x8*)&ps[l16 * 72 + quad * 8];
        s16x8 pa1 = *(const s16x8*)&ps[l16 * 72 + 32 + quad * 8];

        // ---- O += P V  (B-frag from Vt rows: dim-major, key-contiguous)
#pragma unroll
        for (int nt = 0; nt < 4; nt++) {
            const ushort_t* vp = vbase + (size_t)(nt * 16 + l16) * NN + key0 + quad * 8;
            s16x8 vf0 = *(const s16x8*)vp;
            s16x8 vf1 = *(const s16x8*)(vp + 32);
            o[nt] = MFMA16(pa0, vf0, o[nt]);
            o[nt] = MFMA16(pa1, vf1, o[nt]);
        }
    }

    float inv[4];
#pragma unroll
    for (int r = 0; r < 4; r++) inv[r] = 1.0f / l[r];
#pragma unroll
    for (int nt = 0; nt < 4; nt++)
#pragma unroll
        for (int r = 0; r < 4; r++)
            Ob[(size_t)(b * NN + row0 + quad * 4 + r) * D_MODEL + h * 64 + nt * 16 + l16]
                = f2b(o[nt][r] * inv[r]);
}

// ---------------------------------------------------------------------------
extern "C" void kernel_launch(void* const* d_in, const int* in_sizes, int n_in,
                              void* d_out, int out_size, void* d_ws, size_t ws_size,
                              hipStream_t stream)
{
    const float* x    = (const float*)d_in[0];
    const float* cosp = (const float*)d_in[1];
    const float* sinp = (const float*)d_in[2];
    const float* Wq   = (const float*)d_in[3];
    const float* Wk   = (const float*)d_in[4];
    const float* Wv   = (const float*)d_in[5];
    const float* Wo   = (const float*)d_in[6];
    float* out = (float*)d_out;

    char* w = (char*)d_ws;
    ushort_t* xb     = (ushort_t*)w;                       w += (size_t)MROWS * D_MODEL * 2;
    ushort_t* WqkvT  = (ushort_t*)w;                       w += (size_t)QKVN * D_MODEL * 2;
    ushort_t* WoT    = (ushort_t*)w;                       w += (size_t)D_MODEL * D_MODEL * 2;
    float*    QKVf   = (float*)w;                          w += (size_t)MROWS * QKVN * 4;
    ushort_t* Qbuf   = (ushort_t*)w;                       w += (size_t)MROWS * D_MODEL * 2;
    ushort_t* Kbuf   = (ushort_t*)w;                       w += (size_t)MROWS * KVDIM * 2;
    ushort_t* Vt     = (ushort_t*)w;                       w += (size_t)MROWS * KVDIM * 2;
    ushort_t* Obuf   = (ushort_t*)w;

    // --- prep: casts & weight transposes
    cast_kernel<<<(MROWS * D_MODEL / 4 + 255) / 256, 256, 0, stream>>>(
        x, xb, MROWS * D_MODEL / 4);
    transpose_cast<<<dim3(D_MODEL / 32, D_MODEL / 32), 256, 0, stream>>>(
        Wq, WqkvT, D_MODEL, D_MODEL);
    transpose_cast<<<dim3(KVDIM / 32, D_MODEL / 32), 256, 0, stream>>>(
        Wk, WqkvT + (size_t)1024 * D_MODEL, D_MODEL, KVDIM);
    transpose_cast<<<dim3(KVDIM / 32, D_MODEL / 32), 256, 0, stream>>>(
        Wv, WqkvT + (size_t)1280 * D_MODEL, D_MODEL, KVDIM);
    transpose_cast<<<dim3(D_MODEL / 32, D_MODEL / 32), 256, 0, stream>>>(
        Wo, WoT, D_MODEL, D_MODEL);

    // --- fused QKV projection
    gemm_bt<<<dim3(QKVN / 128, MROWS / 128), 256, 0, stream>>>(
        xb, WqkvT, QKVf, MROWS, QKVN, D_MODEL);

    // --- rope + relayout (Q,K), V transpose
    rope_kernel<<<(NQW + NKW) / 256, 256, 0, stream>>>(QKVf, cosp, sinp, Qbuf, Kbuf);
    vtrans_kernel<<<dim3(NN / 32, KVDIM / 32, BB), 256, 0, stream>>>(QKVf, Vt);

    // --- attention
    attn_mfma<<<dim3(NN / 64, NHEADS, BB), 256, 0, stream>>>(Qbuf, Kbuf, Vt, Obuf);

    // --- output projection
    gemm_bt<<<dim3(D_MODEL / 128, MROWS / 128), 256, 0, stream>>>(
        Obuf, WoT, out, MROWS, D_MODEL, D_MODEL);
}